// Round 13
// baseline (53.904 us; speedup 1.0000x reference)
//
#include <hip/hip_runtime.h>

#define C_DIM 19
#define G_DIM 8
#define H_DIM 512
#define W_DIM 512
#define B_DIM 4
#define PLANE (H_DIM * W_DIM)
#define NPIX  (B_DIM * PLANE)
#define NT    256
#define QCOLS 288   // staged Qg cols per row: [x0-16, x0+272)

__device__ __forceinline__ unsigned bf16rne(float f) {
    unsigned x = __float_as_uint(f);
    return (x + 0x7fffu + ((x >> 16) & 1u)) >> 16;
}
__device__ __forceinline__ float up_lo(unsigned u) { return __uint_as_float(u << 16); }
__device__ __forceinline__ float up_hi(unsigned u) { return __uint_as_float(u & 0xffff0000u); }

// async global -> LDS, 16 B per active lane, no VGPR destination.
// LDS dest = wave-uniform base + lane*16; global src is per-lane.
__device__ __forceinline__ void gload_lds16(const void* g, void* l) {
    __builtin_amdgcn_global_load_lds(
        (const __attribute__((address_space(1))) unsigned int*)g,
        (__attribute__((address_space(3))) unsigned int*)l,
        16, 0, 0);
}

// E = softmax(100*matrix over g): E4[c][0]=g0..3, E4[c][1]=g4..7.  NO sync inside.
__device__ __forceinline__ void build_E_nosync(const float* __restrict__ matrix,
                                               float4 (*E4)[2], int tid) {
    if (tid < C_DIM) {
        const int c = tid;
        float m[G_DIM];
        float mx = -1e30f;
        #pragma unroll
        for (int g = 0; g < G_DIM; ++g) {
            m[g] = 100.0f * matrix[g * C_DIM + c];
            mx = fmaxf(mx, m[g]);
        }
        float s = 0.0f;
        #pragma unroll
        for (int g = 0; g < G_DIM; ++g) { m[g] = __expf(m[g] - mx); s += m[g]; }
        const float inv = 1.0f / s;
        E4[c][0] = make_float4(m[0]*inv, m[1]*inv, m[2]*inv, m[3]*inv);
        E4[c][1] = make_float4(m[4]*inv, m[5]*inv, m[6]*inv, m[7]*inv);
    }
}

// ---- K1: softmax over C + encode to G, 2 px/thread; Qg packed [b][h][w][g] bf16 ----
__global__ __launch_bounds__(NT, 4)
void qg_encode(const float* __restrict__ logit,
               const float* __restrict__ matrix,
               uint4* __restrict__ Qg)
{
    __shared__ float4 E4[C_DIM][2];
    build_E_nosync(matrix, E4, threadIdx.x);
    __syncthreads();

    const int bid = blockIdx.x;
    const int swz = (bid & 7) * (NPIX / (2 * NT) / 8) + (bid >> 3);
    const int t   = swz * NT + threadIdx.x;
    const int px0 = t * 2;
    const int b   = px0 >> 18;
    const int pix = px0 & (PLANE - 1);
    const float* __restrict__ p = logit + (size_t)b * C_DIM * PLANE + pix;

    float eg[G_DIM][2];
    #pragma unroll
    for (int g = 0; g < G_DIM; ++g) { eg[g][0] = 0.0f; eg[g][1] = 0.0f; }
    float s0 = 0.0f, s1 = 0.0f;

    #pragma unroll
    for (int c = 0; c < C_DIM; ++c) {
        const float2 lv = *(const float2*)(p + (size_t)c * PLANE);
        const float e0 = __expf(lv.x);
        const float e1 = __expf(lv.y);
        s0 += e0; s1 += e1;
        const float4 E0 = E4[c][0];
        const float4 E1 = E4[c][1];
        eg[0][0] = fmaf(E0.x, e0, eg[0][0]);  eg[0][1] = fmaf(E0.x, e1, eg[0][1]);
        eg[1][0] = fmaf(E0.y, e0, eg[1][0]);  eg[1][1] = fmaf(E0.y, e1, eg[1][1]);
        eg[2][0] = fmaf(E0.z, e0, eg[2][0]);  eg[2][1] = fmaf(E0.z, e1, eg[2][1]);
        eg[3][0] = fmaf(E0.w, e0, eg[3][0]);  eg[3][1] = fmaf(E0.w, e1, eg[3][1]);
        eg[4][0] = fmaf(E1.x, e0, eg[4][0]);  eg[4][1] = fmaf(E1.x, e1, eg[4][1]);
        eg[5][0] = fmaf(E1.y, e0, eg[5][0]);  eg[5][1] = fmaf(E1.y, e1, eg[5][1]);
        eg[6][0] = fmaf(E1.z, e0, eg[6][0]);  eg[6][1] = fmaf(E1.z, e1, eg[6][1]);
        eg[7][0] = fmaf(E1.w, e0, eg[7][0]);  eg[7][1] = fmaf(E1.w, e1, eg[7][1]);
    }
    {
        const float inv = 1.0f / s0;
        uint4 u;
        u.x = bf16rne(eg[0][0]*inv) | (bf16rne(eg[1][0]*inv) << 16);
        u.y = bf16rne(eg[2][0]*inv) | (bf16rne(eg[3][0]*inv) << 16);
        u.z = bf16rne(eg[4][0]*inv) | (bf16rne(eg[5][0]*inv) << 16);
        u.w = bf16rne(eg[6][0]*inv) | (bf16rne(eg[7][0]*inv) << 16);
        Qg[px0] = u;
    }
    {
        const float inv = 1.0f / s1;
        uint4 u;
        u.x = bf16rne(eg[0][1]*inv) | (bf16rne(eg[1][1]*inv) << 16);
        u.y = bf16rne(eg[2][1]*inv) | (bf16rne(eg[3][1]*inv) << 16);
        u.z = bf16rne(eg[4][1]*inv) | (bf16rne(eg[5][1]*inv) << 16);
        u.w = bf16rne(eg[6][1]*inv) | (bf16rne(eg[7][1]*inv) << 16);
        Qg[px0 + 1] = u;
    }
}

// ---- K2: EVERYTHING staged via global_load_lds; half-row blocks, 1 px/thread ----
// 4096 blocks x 256 threads: tile = (b, y, x0..x0+255).
__global__ __launch_bounds__(NT)
void crf_decode(const float* __restrict__ F,
                const float* __restrict__ logit,
                const float* __restrict__ matrix,
                const uint4* __restrict__ Qg,
                float* __restrict__ out)
{
    __shared__ float4 E4[C_DIM][2];
    __shared__ uint4  ldsQ[3 * QCOLS];    // 13824 B
    __shared__ float  ldsF[9 * NT];       //  9216 B
    __shared__ float  ldsL[C_DIM * NT];   // 19456 B

    const int tid = threadIdx.x;

    // XCD-chunked bijective swizzle (4096 % 8 == 0, chunk = 512):
    // XCD n handles rows [256n .. 256n+255) of b = n/2-ish — same map as K1's writer.
    const int bid = blockIdx.x;
    const int swz = (bid & 7) * 512 + (bid >> 3);
    const int b   = swz >> 10;
    const int rem = swz & 1023;
    const int y   = rem >> 1;
    const int x0  = (rem & 1) << 8;

    // ---- stage Qg halo: 3 rows x 288 cols, per-lane clamped global src ----
    const int ym[3] = { max(y - 1, 0), y, min(y + 1, H_DIM - 1) };
    const uint4* __restrict__ Qb = Qg + (size_t)b * PLANE;
    #pragma unroll
    for (int r = 0; r < 3; ++r) {
        #pragma unroll
        for (int i = 0; i < 2; ++i) {
            const int u = i * NT + tid;
            if (u < QCOLS) {
                const int gcol = min(max(x0 - 16 + u, 0), W_DIM - 1);
                gload_lds16(Qb + (size_t)ym[r] * W_DIM + gcol,
                            (char*)ldsQ + ((r * QCOLS + i * NT + (tid & ~63)) << 4));
            }
        }
    }

    // ---- stage F: 9 planes x 256 floats = 576 units ----
    const float* __restrict__ Fb = F + (size_t)b * 9 * PLANE + (size_t)y * W_DIM + x0;
    #pragma unroll
    for (int i = 0; i < 3; ++i) {
        const int u = i * NT + tid;
        if (u < 9 * 64) {
            const int k   = u >> 6;       // wave-uniform
            const int c16 = u & 63;
            gload_lds16((const char*)(Fb + (size_t)k * PLANE) + (c16 << 4),
                        (char*)ldsF + ((i * NT + (tid & ~63)) << 4));
        }
    }

    // ---- stage logit: 19 planes x 256 floats = 1216 units ----
    const float* __restrict__ Lb = logit + (size_t)b * C_DIM * PLANE + (size_t)y * W_DIM + x0;
    #pragma unroll
    for (int i = 0; i < 5; ++i) {
        const int u = i * NT + tid;
        if (u < C_DIM * 64) {
            const int k   = u >> 6;       // wave-uniform
            const int c16 = u & 63;
            gload_lds16((const char*)(Lb + (size_t)k * PLANE) + (c16 << 4),
                        (char*)ldsL + ((i * NT + (tid & ~63)) << 4));
        }
    }

    build_E_nosync(matrix, E4, tid);
    __syncthreads();   // drains vmcnt(0): all staged data landed; E4 visible

    // ---- filter: taps from ldsQ (b128, stride-1), weights from ldsF (b32) ----
    const int lx = tid;
    const int xg = x0 + lx;
    const bool vyr[3] = { y > 0, true, y < H_DIM - 1 };
    const bool vxc[3] = { xg > 0, true, xg < W_DIM - 1 };

    float og[G_DIM];
    #pragma unroll
    for (int g = 0; g < G_DIM; ++g) og[g] = 0.0f;

    #pragma unroll
    for (int r = 0; r < 3; ++r) {
        const uint4 qa = ldsQ[r * QCOLS + lx + 15];
        const uint4 qb = ldsQ[r * QCOLS + lx + 16];
        const uint4 qc = ldsQ[r * QCOLS + lx + 17];
        const uint4 qv_[3] = { qa, qb, qc };
        #pragma unroll
        for (int dxi = 0; dxi < 3; ++dxi) {
            const float wv = (vyr[r] & vxc[dxi]) ? ldsF[(r * 3 + dxi) * NT + lx] : 0.0f;
            const uint4 qv = qv_[dxi];
            og[0] = fmaf(wv, up_lo(qv.x), og[0]);
            og[1] = fmaf(wv, up_hi(qv.x), og[1]);
            og[2] = fmaf(wv, up_lo(qv.y), og[2]);
            og[3] = fmaf(wv, up_hi(qv.y), og[3]);
            og[4] = fmaf(wv, up_lo(qv.z), og[4]);
            og[5] = fmaf(wv, up_hi(qv.z), og[5]);
            og[6] = fmaf(wv, up_lo(qv.w), og[6]);
            og[7] = fmaf(wv, up_hi(qv.w), og[7]);
        }
    }

    // ---- decode + subtract + nt-store ----
    float* __restrict__ op = out + (size_t)b * C_DIM * PLANE + (size_t)y * W_DIM + xg;
    #pragma unroll
    for (int c = 0; c < C_DIM; ++c) {
        const float4 E0 = E4[c][0];
        const float4 E1 = E4[c][1];
        float dec = og[0] * E0.x;
        dec = fmaf(og[1], E0.y, dec);
        dec = fmaf(og[2], E0.z, dec);
        dec = fmaf(og[3], E0.w, dec);
        dec = fmaf(og[4], E1.x, dec);
        dec = fmaf(og[5], E1.y, dec);
        dec = fmaf(og[6], E1.z, dec);
        dec = fmaf(og[7], E1.w, dec);
        __builtin_nontemporal_store(ldsL[c * NT + lx] - dec, op + (size_t)c * PLANE);
    }
}

extern "C" void kernel_launch(void* const* d_in, const int* in_sizes, int n_in,
                              void* d_out, int out_size, void* d_ws, size_t ws_size,
                              hipStream_t stream) {
    const float* F      = (const float*)d_in[0];   // [4, 9, 512, 512]
    const float* logit  = (const float*)d_in[1];   // [4, 19, 512, 512]
    const float* matrix = (const float*)d_in[2];   // [8, 19, 1, 1]
    float* out = (float*)d_out;                    // [4, 19, 512, 512]
    uint4* Qg = (uint4*)d_ws;                      // 16.8 MB: [4][512][512] x 8 bf16

    qg_encode <<<NPIX / (2 * NT), NT, 0, stream>>>(logit, matrix, Qg);
    crf_decode<<<NPIX / NT, NT, 0, stream>>>(F, logit, matrix, Qg, out);
}